// Round 1
// baseline (270.746 us; speedup 1.0000x reference)
//
#include <hip/hip_runtime.h>
#include <hip/hip_bf16.h>

#define FIN 128
#define F1 256      // H1*D1
#define H1N 8
#define D1N 32
#define NCLS 40
#define NEG 0.2f

static __device__ __forceinline__ float leaky(float x){ return x >= 0.f ? x : NEG*x; }

// ---------------- CSR build ----------------
__global__ void k_hist(const int* __restrict__ dst, int* __restrict__ deg, int E){
    int e = blockIdx.x*256 + threadIdx.x;
    if (e < E) atomicAdd(&deg[dst[e]], 1);
}

__global__ void k_scan1(const int* __restrict__ deg, int* __restrict__ rowptr,
                        int* __restrict__ bsum, int n){
    __shared__ int s[256];
    int t = threadIdx.x;
    int i = blockIdx.x*256 + t;
    int v = (i < n) ? deg[i] : 0;
    s[t] = v;
    __syncthreads();
    for (int off=1; off<256; off<<=1){
        int y = (t >= off) ? s[t-off] : 0;
        __syncthreads();
        if (t >= off) s[t] += y;
        __syncthreads();
    }
    if (i < n) rowptr[i] = s[t] - v;          // exclusive, pre-offset
    if (t == 255) bsum[blockIdx.x] = s[255];
}

__global__ void k_scan2(int* __restrict__ rowptr, const int* __restrict__ bsum,
                        int n, int E){
    int b = blockIdx.x;
    int l = threadIdx.x & 63;
    int v = 0;
    for (int j = l; j < b; j += 64) v += bsum[j];
    for (int msk=1; msk<64; msk<<=1) v += __shfl_xor(v, msk);
    int i = b*256 + threadIdx.x;
    if (i < n) rowptr[i] += v;
    else if (i == n) rowptr[n] = E;
}

__global__ void k_scatter(const int* __restrict__ src, const int* __restrict__ dst,
                          const int* __restrict__ rowptr, int* __restrict__ deg,
                          int* __restrict__ adj, int E){
    int e = blockIdx.x*256 + threadIdx.x;
    if (e < E){
        int d = dst[e];
        int pos = atomicSub(&deg[d], 1) - 1;
        adj[rowptr[d] + pos] = src[e];
    }
}

// ---------------- GEMM1: [M,128] @ [128,256] ----------------
__global__ __launch_bounds__(256) void k_gemm1(const float* __restrict__ X,
                                               const float* __restrict__ W,
                                               float* __restrict__ C, int M){
    __shared__ float As[32][68];   // transposed: As[k][m]
    __shared__ float Bs[32][68];   // Bs[k][n]
    int t = threadIdx.x;
    int bx = blockIdx.x & 3;
    int by = blockIdx.x >> 2;
    int m0 = by*64, n0 = bx*64;
    int ty = t >> 4, tx = t & 15;
    float acc[4][4] = {};
    for (int k0 = 0; k0 < FIN; k0 += 32){
        #pragma unroll
        for (int p=0;p<2;p++){
            int f = t + p*256;
            int m = f >> 3;
            int kq = f & 7;
            int row = m0 + m;
            float4 v = make_float4(0.f,0.f,0.f,0.f);
            if (row < M) v = *(const float4*)&X[row*FIN + k0 + kq*4];
            As[kq*4+0][m] = v.x; As[kq*4+1][m] = v.y;
            As[kq*4+2][m] = v.z; As[kq*4+3][m] = v.w;
        }
        #pragma unroll
        for (int p=0;p<2;p++){
            int f = t + p*256;
            int kk = f >> 4;
            int nq = f & 15;
            float4 v = *(const float4*)&W[(size_t)(k0+kk)*F1 + n0 + nq*4];
            *(float4*)&Bs[kk][nq*4] = v;
        }
        __syncthreads();
        #pragma unroll
        for (int kk=0; kk<32; kk++){
            float4 a4 = *(const float4*)&As[kk][ty*4];
            float4 b4 = *(const float4*)&Bs[kk][tx*4];
            float av[4] = {a4.x,a4.y,a4.z,a4.w};
            float bv[4] = {b4.x,b4.y,b4.z,b4.w};
            #pragma unroll
            for (int r=0;r<4;r++)
                #pragma unroll
                for (int c=0;c<4;c++)
                    acc[r][c] = fmaf(av[r], bv[c], acc[r][c]);
        }
        __syncthreads();
    }
    #pragma unroll
    for (int r=0;r<4;r++){
        int row = m0 + ty*4 + r;
        if (row < M)
            *(float4*)&C[(size_t)row*F1 + n0 + tx*4] =
                make_float4(acc[r][0],acc[r][1],acc[r][2],acc[r][3]);
    }
}

// ---------------- el/er layer 1: wave per node ----------------
__global__ __launch_bounds__(256) void k_elr1(const float* __restrict__ ft,
                      const float* __restrict__ al, const float* __restrict__ ar,
                      float* __restrict__ el, float* __restrict__ er, int n){
    int node = (blockIdx.x*256 + threadIdx.x) >> 6;
    int l = threadIdx.x & 63;
    if (node >= n) return;
    int h = l >> 3, q = l & 7;
    float4 f = *(const float4*)&ft[(size_t)node*F1 + l*4];
    float4 wl = *(const float4*)&al[h*D1N + q*4];
    float4 wr = *(const float4*)&ar[h*D1N + q*4];
    float pl = f.x*wl.x + f.y*wl.y + f.z*wl.z + f.w*wl.w;
    float pr = f.x*wr.x + f.y*wr.y + f.z*wr.z + f.w*wr.w;
    #pragma unroll
    for (int m=1;m<8;m<<=1){ pl += __shfl_xor(pl,m); pr += __shfl_xor(pr,m); }
    if (q == 0){ el[node*H1N + h] = pl; er[node*H1N + h] = pr; }
}

// ---------------- layer-1 softmax + aggregation + relu: wave per node ----------------
__global__ __launch_bounds__(256) void k_agg1(const float* __restrict__ ft,
                      const float* __restrict__ el, const float* __restrict__ er,
                      const int* __restrict__ rowptr, const int* __restrict__ adj,
                      float* __restrict__ hout, int n){
    int node = (blockIdx.x*256 + threadIdx.x) >> 6;
    int l = threadIdx.x & 63;
    if (node >= n) return;
    int rs = rowptr[node];
    int deg = rowptr[node+1] - rs;

    // pass 1: online softmax stats per head (lane = 8 edges x 8 heads)
    int h = l & 7, je = l >> 3;
    float erh = er[node*H1N + h];
    float m = -1e30f, ssum = 0.f;
    for (int j0 = 0; j0 < deg; j0 += 8){
        int j = j0 + je;
        if (j < deg){
            int s = adj[rs + j];
            float e = leaky(el[s*H1N + h] + erh);
            if (e > m){ ssum = ssum*__expf(m - e) + 1.f; m = e; }
            else ssum += __expf(e - m);
        }
    }
    #pragma unroll
    for (int msk=8; msk<64; msk<<=1){
        float m2 = __shfl_xor(m, msk);
        float s2 = __shfl_xor(ssum, msk);
        float nm = fmaxf(m, m2);
        ssum = ssum*__expf(m - nm) + s2*__expf(m2 - nm);
        m = nm;
    }

    // pass 2: lane owns elements [4l,4l+4) => head h2 = l>>3
    int h2 = l >> 3;
    float m2 = __shfl(m, h2);
    float s2 = __shfl(ssum, h2);
    float inv = 1.f / fmaxf(s2, 1e-16f);
    float erh2 = er[node*H1N + h2];
    float ax=0.f, ay=0.f, az=0.f, aw=0.f;
    for (int j = 0; j < deg; j++){
        int s = adj[rs + j];
        float e = leaky(el[s*H1N + h2] + erh2);
        float a = __expf(e - m2) * inv;
        float4 f = *(const float4*)&ft[(size_t)s*F1 + l*4];
        ax = fmaf(a, f.x, ax); ay = fmaf(a, f.y, ay);
        az = fmaf(a, f.z, az); aw = fmaf(a, f.w, aw);
    }
    *(float4*)&hout[(size_t)node*F1 + l*4] =
        make_float4(fmaxf(ax,0.f), fmaxf(ay,0.f), fmaxf(az,0.f), fmaxf(aw,0.f));
}

// ---------------- GEMM2: [M,256] @ [256,40] ----------------
__global__ __launch_bounds__(256) void k_gemm2(const float* __restrict__ Hm,
                                               const float* __restrict__ W,
                                               float* __restrict__ C, int M){
    __shared__ float W2s[F1*NCLS];   // [k][c] flat
    __shared__ float hs[128][33];
    int t = threadIdx.x;
    for (int i = t; i < F1*NCLS; i += 256) W2s[i] = W[i];
    int r0 = blockIdx.x*128;
    int rr = t & 63;
    int cg = t >> 6;
    int c0 = cg*10;
    float acc[2][10] = {};
    for (int k0 = 0; k0 < F1; k0 += 32){
        __syncthreads();
        #pragma unroll
        for (int p=0;p<4;p++){
            int f = t + p*256;
            int row = f >> 3;
            int kq = f & 7;
            int gr = r0 + row;
            float4 v = make_float4(0.f,0.f,0.f,0.f);
            if (gr < M) v = *(const float4*)&Hm[(size_t)gr*F1 + k0 + kq*4];
            hs[row][kq*4+0] = v.x; hs[row][kq*4+1] = v.y;
            hs[row][kq*4+2] = v.z; hs[row][kq*4+3] = v.w;
        }
        __syncthreads();
        #pragma unroll
        for (int k=0;k<32;k++){
            float a0 = hs[rr][k], a1 = hs[rr+64][k];
            const float* wp = &W2s[(k0+k)*NCLS + c0];
            #pragma unroll
            for (int c=0;c<10;c+=2){
                float2 w = *(const float2*)&wp[c];
                acc[0][c]   = fmaf(a0, w.x, acc[0][c]);
                acc[0][c+1] = fmaf(a0, w.y, acc[0][c+1]);
                acc[1][c]   = fmaf(a1, w.x, acc[1][c]);
                acc[1][c+1] = fmaf(a1, w.y, acc[1][c+1]);
            }
        }
    }
    #pragma unroll
    for (int i=0;i<2;i++){
        int gr = r0 + rr + i*64;
        if (gr < M){
            #pragma unroll
            for (int c=0;c<10;c++) C[(size_t)gr*NCLS + c0 + c] = acc[i][c];
        }
    }
}

// ---------------- el/er layer 2 ----------------
__global__ __launch_bounds__(256) void k_elr2(const float* __restrict__ ft2,
                      const float* __restrict__ al, const float* __restrict__ ar,
                      float* __restrict__ el, float* __restrict__ er, int n){
    int node = (blockIdx.x*256 + threadIdx.x) >> 6;
    int l = threadIdx.x & 63;
    if (node >= n) return;
    float v  = (l < NCLS) ? ft2[(size_t)node*NCLS + l] : 0.f;
    float pl = (l < NCLS) ? v*al[l] : 0.f;
    float pr = (l < NCLS) ? v*ar[l] : 0.f;
    #pragma unroll
    for (int m=1;m<64;m<<=1){ pl += __shfl_xor(pl,m); pr += __shfl_xor(pr,m); }
    if (l == 0){ el[node] = pl; er[node] = pr; }
}

// ---------------- layer-2 softmax + aggregation ----------------
__global__ __launch_bounds__(256) void k_agg2(const float* __restrict__ ft2,
                      const float* __restrict__ el, const float* __restrict__ er,
                      const int* __restrict__ rowptr, const int* __restrict__ adj,
                      float* __restrict__ out, int n){
    int node = (blockIdx.x*256 + threadIdx.x) >> 6;
    int l = threadIdx.x & 63;
    if (node >= n) return;
    int rs = rowptr[node];
    int deg = rowptr[node+1] - rs;
    float ern = er[node];
    float m = -1e30f, ssum = 0.f;
    for (int j = l; j < deg; j += 64){
        int s = adj[rs + j];
        float e = leaky(el[s] + ern);
        if (e > m){ ssum = ssum*__expf(m - e) + 1.f; m = e; }
        else ssum += __expf(e - m);
    }
    #pragma unroll
    for (int msk=1; msk<64; msk<<=1){
        float mm = __shfl_xor(m, msk);
        float s2 = __shfl_xor(ssum, msk);
        float nm = fmaxf(m, mm);
        ssum = ssum*__expf(m - nm) + s2*__expf(mm - nm);
        m = nm;
    }
    float inv = 1.f / fmaxf(ssum, 1e-16f);
    float acc = 0.f;
    for (int j = 0; j < deg; j++){
        int s = adj[rs + j];
        float e = leaky(el[s] + ern);
        float a = __expf(e - m) * inv;
        if (l < NCLS) acc = fmaf(a, ft2[(size_t)s*NCLS + l], acc);
    }
    if (l < NCLS) out[(size_t)node*NCLS + l] = acc;
}

extern "C" void kernel_launch(void* const* d_in, const int* in_sizes, int n_in,
                              void* d_out, int out_size, void* d_ws, size_t ws_size,
                              hipStream_t stream){
    const float* x   = (const float*)d_in[0];
    const float* W1  = (const float*)d_in[1];
    const float* al1 = (const float*)d_in[2];
    const float* ar1 = (const float*)d_in[3];
    const float* W2  = (const float*)d_in[4];
    const float* al2 = (const float*)d_in[5];
    const float* ar2 = (const float*)d_in[6];
    const int*   src = (const int*)d_in[7];
    const int*   dst = (const int*)d_in[8];
    int E = in_sizes[7];
    int n = in_sizes[0] / FIN;   // 20000

    char* ws = (char*)d_ws;
    size_t off = 0;
    auto alloc = [&](size_t bytes)->void*{
        void* p = ws + off; off += (bytes + 255) & ~(size_t)255; return p;
    };
    float* ft1   = (float*)alloc((size_t)n*F1*4);
    float* hbuf  = (float*)alloc((size_t)n*F1*4);
    float* el1   = (float*)alloc((size_t)n*H1N*4);
    float* er1   = (float*)alloc((size_t)n*H1N*4);
    float* ft2   = (float*)alloc((size_t)n*NCLS*4);
    float* el2   = (float*)alloc((size_t)n*4);
    float* er2   = (float*)alloc((size_t)n*4);
    int*   rowptr= (int*)alloc((size_t)(n+1)*4);
    int*   deg   = (int*)alloc((size_t)n*4);
    int*   bsum  = (int*)alloc((size_t)((n+255)/256)*4);
    int*   adj   = (int*)alloc((size_t)E*4);

    int nb_e = (E + 255)/256;
    int nb_n = (n + 255)/256;

    hipMemsetAsync(deg, 0, (size_t)n*4, stream);
    k_hist   <<<nb_e, 256, 0, stream>>>(dst, deg, E);
    k_scan1  <<<nb_n, 256, 0, stream>>>(deg, rowptr, bsum, n);
    k_scan2  <<<(n+1+255)/256, 256, 0, stream>>>(rowptr, bsum, n, E);
    k_scatter<<<nb_e, 256, 0, stream>>>(src, dst, rowptr, deg, adj, E);

    k_gemm1  <<<((n+63)/64)*4, 256, 0, stream>>>(x, W1, ft1, n);
    k_elr1   <<<(n+3)/4, 256, 0, stream>>>(ft1, al1, ar1, el1, er1, n);
    k_agg1   <<<(n+3)/4, 256, 0, stream>>>(ft1, el1, er1, rowptr, adj, hbuf, n);

    k_gemm2  <<<(n+127)/128, 256, 0, stream>>>(hbuf, W2, ft2, n);
    k_elr2   <<<(n+3)/4, 256, 0, stream>>>(ft2, al2, ar2, el2, er2, n);
    k_agg2   <<<(n+3)/4, 256, 0, stream>>>(ft2, el2, er2, rowptr, adj, (float*)d_out, n);
}

// Round 5
// 269.505 us; speedup vs baseline: 1.0046x; 1.0046x over previous
//
#include <hip/hip_runtime.h>
#include <hip/hip_bf16.h>

#define FIN 128
#define F1 256      // H1*D1
#define H1N 8
#define D1N 32
#define NCLS 40
#define FT2P 64     // padded row stride for ft2
#define NEG 0.2f

static __device__ __forceinline__ float leaky(float x){ return x >= 0.f ? x : NEG*x; }

// ---------------- CSR build ----------------
__global__ void k_hist(const int* __restrict__ dst, int* __restrict__ deg, int E){
    int e = blockIdx.x*256 + threadIdx.x;
    if (e < E) atomicAdd(&deg[dst[e]], 1);
}

// single-block exclusive scan over deg[0..n) -> rowptr[0..n]
__global__ __launch_bounds__(1024) void k_scan(const int* __restrict__ deg,
                                               int* __restrict__ rowptr,
                                               int n, int E){
    __shared__ int s[1024];
    int t = threadIdx.x;
    int per = (n + 1023) / 1024;
    int base = t * per;
    int sum = 0;
    for (int i = 0; i < per; i++){
        int idx = base + i;
        if (idx < n) sum += deg[idx];
    }
    s[t] = sum;
    __syncthreads();
    for (int off = 1; off < 1024; off <<= 1){
        int v = (t >= off) ? s[t-off] : 0;
        __syncthreads();
        s[t] += v;
        __syncthreads();
    }
    int run = s[t] - sum;     // exclusive prefix of this chunk
    for (int i = 0; i < per; i++){
        int idx = base + i;
        if (idx < n){ rowptr[idx] = run; run += deg[idx]; }
    }
    if (t == 1023) rowptr[n] = E;
}

__global__ void k_scatter(const int* __restrict__ src, const int* __restrict__ dst,
                          const int* __restrict__ rowptr, int* __restrict__ deg,
                          int* __restrict__ adj, int E){
    int e = blockIdx.x*256 + threadIdx.x;
    if (e < E){
        int d = dst[e];
        int pos = atomicSub(&deg[d], 1) - 1;
        adj[rowptr[d] + pos] = src[e];
    }
}

// ---------------- GEMM1: [M,128] @ [128,256] ----------------
__global__ __launch_bounds__(256) void k_gemm1(const float* __restrict__ X,
                                               const float* __restrict__ W,
                                               float* __restrict__ C, int M){
    __shared__ float As[32][68];   // transposed: As[k][m]
    __shared__ float Bs[32][68];   // Bs[k][n]
    int t = threadIdx.x;
    int bx = blockIdx.x & 3;
    int by = blockIdx.x >> 2;
    int m0 = by*64, n0 = bx*64;
    int ty = t >> 4, tx = t & 15;
    float acc[4][4] = {};
    for (int k0 = 0; k0 < FIN; k0 += 32){
        #pragma unroll
        for (int p=0;p<2;p++){
            int f = t + p*256;
            int m = f >> 3;
            int kq = f & 7;
            int row = m0 + m;
            float4 v = make_float4(0.f,0.f,0.f,0.f);
            if (row < M) v = *(const float4*)&X[row*FIN + k0 + kq*4];
            As[kq*4+0][m] = v.x; As[kq*4+1][m] = v.y;
            As[kq*4+2][m] = v.z; As[kq*4+3][m] = v.w;
        }
        #pragma unroll
        for (int p=0;p<2;p++){
            int f = t + p*256;
            int kk = f >> 4;
            int nq = f & 15;
            float4 v = *(const float4*)&W[(size_t)(k0+kk)*F1 + n0 + nq*4];
            *(float4*)&Bs[kk][nq*4] = v;
        }
        __syncthreads();
        #pragma unroll
        for (int kk=0; kk<32; kk++){
            float4 a4 = *(const float4*)&As[kk][ty*4];
            float4 b4 = *(const float4*)&Bs[kk][tx*4];
            float av[4] = {a4.x,a4.y,a4.z,a4.w};
            float bv[4] = {b4.x,b4.y,b4.z,b4.w};
            #pragma unroll
            for (int r=0;r<4;r++)
                #pragma unroll
                for (int c=0;c<4;c++)
                    acc[r][c] = fmaf(av[r], bv[c], acc[r][c]);
        }
        __syncthreads();
    }
    #pragma unroll
    for (int r=0;r<4;r++){
        int row = m0 + ty*4 + r;
        if (row < M)
            *(float4*)&C[(size_t)row*F1 + n0 + tx*4] =
                make_float4(acc[r][0],acc[r][1],acc[r][2],acc[r][3]);
    }
}

// ---------------- el/er layer 1: wave per node ----------------
__global__ __launch_bounds__(256) void k_elr1(const float* __restrict__ ft,
                      const float* __restrict__ al, const float* __restrict__ ar,
                      float* __restrict__ el, float* __restrict__ er, int n){
    int node = (blockIdx.x*256 + threadIdx.x) >> 6;
    int l = threadIdx.x & 63;
    if (node >= n) return;
    int h = l >> 3, q = l & 7;
    float4 f = *(const float4*)&ft[(size_t)node*F1 + l*4];
    float4 wl = *(const float4*)&al[h*D1N + q*4];
    float4 wr = *(const float4*)&ar[h*D1N + q*4];
    float pl = f.x*wl.x + f.y*wl.y + f.z*wl.z + f.w*wl.w;
    float pr = f.x*wr.x + f.y*wr.y + f.z*wr.z + f.w*wr.w;
    #pragma unroll
    for (int m=1;m<8;m<<=1){ pl += __shfl_xor(pl,m); pr += __shfl_xor(pr,m); }
    if (q == 0){ el[node*H1N + h] = pl; er[node*H1N + h] = pr; }
}

// ---------------- layer-1 softmax + aggregation + relu: wave per node ----------------
__global__ __launch_bounds__(256) void k_agg1(const float* __restrict__ ft,
                      const float* __restrict__ el, const float* __restrict__ er,
                      const int* __restrict__ rowptr, const int* __restrict__ adj,
                      float* __restrict__ hout, int n){
    int node = (blockIdx.x*256 + threadIdx.x) >> 6;
    int l = threadIdx.x & 63;
    if (node >= n) return;
    int rs = rowptr[node];
    int deg = rowptr[node+1] - rs;

    // pass 1: online softmax stats per head (lane = 8 edges x 8 heads)
    int h = l & 7, je = l >> 3;
    float erh = er[node*H1N + h];
    float m = -1e30f, ssum = 0.f;
    for (int j0 = 0; j0 < deg; j0 += 8){
        int j = j0 + je;
        if (j < deg){
            int s = adj[rs + j];
            float e = leaky(el[s*H1N + h] + erh);
            if (e > m){ ssum = ssum*__expf(m - e) + 1.f; m = e; }
            else ssum += __expf(e - m);
        }
    }
    #pragma unroll
    for (int msk=8; msk<64; msk<<=1){
        float m2 = __shfl_xor(m, msk);
        float s2 = __shfl_xor(ssum, msk);
        float nm = fmaxf(m, m2);
        ssum = ssum*__expf(m - nm) + s2*__expf(m2 - nm);
        m = nm;
    }

    // pass 2: lane owns elements [4l,4l+4) => head h2 = l>>3
    int h2 = l >> 3;
    float m2 = __shfl(m, h2);
    float s2 = __shfl(ssum, h2);
    float inv = 1.f / fmaxf(s2, 1e-16f);
    float erh2 = er[node*H1N + h2];
    float ax=0.f, ay=0.f, az=0.f, aw=0.f;
    int j = 0;
    for (; j + 4 <= deg; j += 4){
        int s0 = adj[rs+j+0];
        int s1 = adj[rs+j+1];
        int s2e= adj[rs+j+2];
        int s3 = adj[rs+j+3];
        float e0 = leaky(el[s0*H1N + h2] + erh2);
        float e1 = leaky(el[s1*H1N + h2] + erh2);
        float e2 = leaky(el[s2e*H1N + h2] + erh2);
        float e3 = leaky(el[s3*H1N + h2] + erh2);
        float a0 = __expf(e0 - m2);
        float a1 = __expf(e1 - m2);
        float a2 = __expf(e2 - m2);
        float a3 = __expf(e3 - m2);
        float4 f0 = *(const float4*)&ft[(size_t)s0*F1 + l*4];
        float4 f1 = *(const float4*)&ft[(size_t)s1*F1 + l*4];
        float4 f2 = *(const float4*)&ft[(size_t)s2e*F1 + l*4];
        float4 f3 = *(const float4*)&ft[(size_t)s3*F1 + l*4];
        ax = fmaf(a0,f0.x, fmaf(a1,f1.x, fmaf(a2,f2.x, fmaf(a3,f3.x, ax))));
        ay = fmaf(a0,f0.y, fmaf(a1,f1.y, fmaf(a2,f2.y, fmaf(a3,f3.y, ay))));
        az = fmaf(a0,f0.z, fmaf(a1,f1.z, fmaf(a2,f2.z, fmaf(a3,f3.z, az))));
        aw = fmaf(a0,f0.w, fmaf(a1,f1.w, fmaf(a2,f2.w, fmaf(a3,f3.w, aw))));
    }
    for (; j < deg; j++){
        int s = adj[rs + j];
        float e = leaky(el[s*H1N + h2] + erh2);
        float a = __expf(e - m2);
        float4 f = *(const float4*)&ft[(size_t)s*F1 + l*4];
        ax = fmaf(a, f.x, ax); ay = fmaf(a, f.y, ay);
        az = fmaf(a, f.z, az); aw = fmaf(a, f.w, aw);
    }
    ax *= inv; ay *= inv; az *= inv; aw *= inv;
    *(float4*)&hout[(size_t)node*F1 + l*4] =
        make_float4(fmaxf(ax,0.f), fmaxf(ay,0.f), fmaxf(az,0.f), fmaxf(aw,0.f));
}

// ---------------- GEMM2: [M,256] @ [256,40] -> padded [M,64] ----------------
__global__ __launch_bounds__(256) void k_gemm2(const float* __restrict__ Hm,
                                               const float* __restrict__ W,
                                               float* __restrict__ C, int M){
    __shared__ float W2s[F1*NCLS];   // [k][c] flat
    __shared__ float hs[128][33];
    int t = threadIdx.x;
    for (int i = t; i < F1*NCLS; i += 256) W2s[i] = W[i];
    int r0 = blockIdx.x*128;
    int rr = t & 63;
    int cg = t >> 6;
    int c0 = cg*10;
    float acc[2][10] = {};
    for (int k0 = 0; k0 < F1; k0 += 32){
        __syncthreads();
        #pragma unroll
        for (int p=0;p<4;p++){
            int f = t + p*256;
            int row = f >> 3;
            int kq = f & 7;
            int gr = r0 + row;
            float4 v = make_float4(0.f,0.f,0.f,0.f);
            if (gr < M) v = *(const float4*)&Hm[(size_t)gr*F1 + k0 + kq*4];
            hs[row][kq*4+0] = v.x; hs[row][kq*4+1] = v.y;
            hs[row][kq*4+2] = v.z; hs[row][kq*4+3] = v.w;
        }
        __syncthreads();
        #pragma unroll
        for (int k=0;k<32;k++){
            float a0 = hs[rr][k], a1 = hs[rr+64][k];
            const float* wp = &W2s[(k0+k)*NCLS + c0];
            #pragma unroll
            for (int c=0;c<10;c+=2){
                float2 w = *(const float2*)&wp[c];
                acc[0][c]   = fmaf(a0, w.x, acc[0][c]);
                acc[0][c+1] = fmaf(a0, w.y, acc[0][c+1]);
                acc[1][c]   = fmaf(a1, w.x, acc[1][c]);
                acc[1][c+1] = fmaf(a1, w.y, acc[1][c+1]);
            }
        }
    }
    #pragma unroll
    for (int i=0;i<2;i++){
        int gr = r0 + rr + i*64;
        if (gr < M){
            #pragma unroll
            for (int c=0;c<10;c++) C[(size_t)gr*FT2P + c0 + c] = acc[i][c];
        }
    }
}

// ---------------- el/er layer 2 ----------------
__global__ __launch_bounds__(256) void k_elr2(const float* __restrict__ ft2,
                      const float* __restrict__ al, const float* __restrict__ ar,
                      float* __restrict__ el, float* __restrict__ er, int n){
    int node = (blockIdx.x*256 + threadIdx.x) >> 6;
    int l = threadIdx.x & 63;
    if (node >= n) return;
    float v  = (l < NCLS) ? ft2[(size_t)node*FT2P + l] : 0.f;
    float pl = (l < NCLS) ? v*al[l] : 0.f;
    float pr = (l < NCLS) ? v*ar[l] : 0.f;
    #pragma unroll
    for (int m=1;m<64;m<<=1){ pl += __shfl_xor(pl,m); pr += __shfl_xor(pr,m); }
    if (l == 0){ el[node] = pl; er[node] = pr; }
}

// ---------------- layer-2 softmax + aggregation ----------------
__global__ __launch_bounds__(256) void k_agg2(const float* __restrict__ ft2,
                      const float* __restrict__ el, const float* __restrict__ er,
                      const int* __restrict__ rowptr, const int* __restrict__ adj,
                      float* __restrict__ out, int n){
    int node = (blockIdx.x*256 + threadIdx.x) >> 6;
    int l = threadIdx.x & 63;
    if (node >= n) return;
    int rs = rowptr[node];
    int deg = rowptr[node+1] - rs;
    float ern = er[node];
    float m = -1e30f, ssum = 0.f;
    for (int j = l; j < deg; j += 64){
        int s = adj[rs + j];
        float e = leaky(el[s] + ern);
        if (e > m){ ssum = ssum*__expf(m - e) + 1.f; m = e; }
        else ssum += __expf(e - m);
    }
    #pragma unroll
    for (int msk=1; msk<64; msk<<=1){
        float mm = __shfl_xor(m, msk);
        float s2 = __shfl_xor(ssum, msk);
        float nm = fmaxf(m, mm);
        ssum = ssum*__expf(m - nm) + s2*__expf(mm - nm);
        m = nm;
    }
    float inv = 1.f / fmaxf(ssum, 1e-16f);
    float acc = 0.f;
    int j = 0;
    for (; j + 4 <= deg; j += 4){
        int s0 = adj[rs+j+0];
        int s1 = adj[rs+j+1];
        int s2e= adj[rs+j+2];
        int s3 = adj[rs+j+3];
        float a0 = __expf(leaky(el[s0] + ern) - m);
        float a1 = __expf(leaky(el[s1] + ern) - m);
        float a2 = __expf(leaky(el[s2e] + ern) - m);
        float a3 = __expf(leaky(el[s3] + ern) - m);
        if (l < NCLS){
            float f0 = ft2[(size_t)s0*FT2P + l];
            float f1 = ft2[(size_t)s1*FT2P + l];
            float f2 = ft2[(size_t)s2e*FT2P + l];
            float f3 = ft2[(size_t)s3*FT2P + l];
            acc = fmaf(a0,f0, fmaf(a1,f1, fmaf(a2,f2, fmaf(a3,f3, acc))));
        }
    }
    for (; j < deg; j++){
        int s = adj[rs + j];
        float a = __expf(leaky(el[s] + ern) - m);
        if (l < NCLS) acc = fmaf(a, ft2[(size_t)s*FT2P + l], acc);
    }
    if (l < NCLS) out[(size_t)node*NCLS + l] = acc * inv;
}

extern "C" void kernel_launch(void* const* d_in, const int* in_sizes, int n_in,
                              void* d_out, int out_size, void* d_ws, size_t ws_size,
                              hipStream_t stream){
    const float* x   = (const float*)d_in[0];
    const float* W1  = (const float*)d_in[1];
    const float* al1 = (const float*)d_in[2];
    const float* ar1 = (const float*)d_in[3];
    const float* W2  = (const float*)d_in[4];
    const float* al2 = (const float*)d_in[5];
    const float* ar2 = (const float*)d_in[6];
    const int*   src = (const int*)d_in[7];
    const int*   dst = (const int*)d_in[8];
    int E = in_sizes[7];
    int n = in_sizes[0] / FIN;   // 20000

    char* ws = (char*)d_ws;
    size_t off = 0;
    auto alloc = [&](size_t bytes)->void*{
        void* p = ws + off; off += (bytes + 255) & ~(size_t)255; return p;
    };
    float* ft1   = (float*)alloc((size_t)n*F1*4);
    float* hbuf  = (float*)alloc((size_t)n*F1*4);
    float* el1   = (float*)alloc((size_t)n*H1N*4);
    float* er1   = (float*)alloc((size_t)n*H1N*4);
    float* ft2   = (float*)alloc((size_t)n*FT2P*4);
    float* el2   = (float*)alloc((size_t)n*4);
    float* er2   = (float*)alloc((size_t)n*4);
    int*   rowptr= (int*)alloc((size_t)(n+1)*4);
    int*   deg   = (int*)alloc((size_t)n*4);
    int*   adj   = (int*)alloc((size_t)E*4);

    int nb_e = (E + 255)/256;
    int nb_n = (n + 255)/256;

    hipMemsetAsync(deg, 0, (size_t)n*4, stream);
    k_hist   <<<nb_e, 256, 0, stream>>>(dst, deg, E);
    k_scan   <<<1, 1024, 0, stream>>>(deg, rowptr, n, E);
    k_scatter<<<nb_e, 256, 0, stream>>>(src, dst, rowptr, deg, adj, E);

    k_gemm1  <<<((n+63)/64)*4, 256, 0, stream>>>(x, W1, ft1, n);
    k_elr1   <<<(n+3)/4, 256, 0, stream>>>(ft1, al1, ar1, el1, er1, n);
    k_agg1   <<<(n+3)/4, 256, 0, stream>>>(ft1, el1, er1, rowptr, adj, hbuf, n);

    k_gemm2  <<<(n+127)/128, 256, 0, stream>>>(hbuf, W2, ft2, n);
    k_elr2   <<<(n+3)/4, 256, 0, stream>>>(ft2, al2, ar2, el2, er2, n);
    k_agg2   <<<(n+3)/4, 256, 0, stream>>>(ft2, el2, er2, rowptr, adj, (float*)d_out, n);
}

// Round 6
// 245.795 us; speedup vs baseline: 1.1015x; 1.0965x over previous
//
#include <hip/hip_runtime.h>
#include <hip/hip_fp16.h>

#define FIN 128
#define F1 256      // H1*D1
#define H1N 8
#define D1N 32
#define NCLS 40
#define FT2P 64     // padded row stride for ft2 (halves)
#define NEG 0.2f

static __device__ __forceinline__ float leaky(float x){ return x >= 0.f ? x : NEG*x; }

// ---------------- CSR build ----------------
__global__ void k_hist(const int* __restrict__ dst, int* __restrict__ deg, int E){
    int e = blockIdx.x*256 + threadIdx.x;
    if (e < E) atomicAdd(&deg[dst[e]], 1);
}

// single-block exclusive scan over deg[0..n) -> rowptr[0..n]
__global__ __launch_bounds__(1024) void k_scan(const int* __restrict__ deg,
                                               int* __restrict__ rowptr,
                                               int n, int E){
    __shared__ int s[1024];
    int t = threadIdx.x;
    int per = (n + 1023) / 1024;
    int base = t * per;
    int sum = 0;
    for (int i = 0; i < per; i++){
        int idx = base + i;
        if (idx < n) sum += deg[idx];
    }
    s[t] = sum;
    __syncthreads();
    for (int off = 1; off < 1024; off <<= 1){
        int v = (t >= off) ? s[t-off] : 0;
        __syncthreads();
        s[t] += v;
        __syncthreads();
    }
    int run = s[t] - sum;
    for (int i = 0; i < per; i++){
        int idx = base + i;
        if (idx < n){ rowptr[idx] = run; run += deg[idx]; }
    }
    if (t == 1023) rowptr[n] = E;
}

__global__ void k_scatter(const int* __restrict__ src, const int* __restrict__ dst,
                          const int* __restrict__ rowptr, int* __restrict__ deg,
                          int* __restrict__ adj, int E){
    int e = blockIdx.x*256 + threadIdx.x;
    if (e < E){
        int d = dst[e];
        int pos = atomicSub(&deg[d], 1) - 1;
        adj[rowptr[d] + pos] = src[e];
    }
}

// ---------------- GEMM1: [M,128]@[128,256] -> fp16 FT + fused el/er ----------------
__global__ __launch_bounds__(256) void k_gemm1(const float* __restrict__ X,
                                               const float* __restrict__ W,
                                               const float* __restrict__ al,
                                               const float* __restrict__ ar,
                                               __half* __restrict__ FT,
                                               float* __restrict__ el,
                                               float* __restrict__ er, int M){
    __shared__ float As[32][68];   // As[k][m]
    __shared__ float Bs[32][68];   // Bs[k][n]
    int t = threadIdx.x;
    int bx = blockIdx.x & 3;
    int by = blockIdx.x >> 2;
    int m0 = by*64, n0 = bx*64;
    int ty = t >> 4, tx = t & 15;
    float acc[4][4] = {};
    for (int k0 = 0; k0 < FIN; k0 += 32){
        #pragma unroll
        for (int p=0;p<2;p++){
            int f = t + p*256;
            int m = f >> 3;
            int kq = f & 7;
            int row = m0 + m;
            float4 v = make_float4(0.f,0.f,0.f,0.f);
            if (row < M) v = *(const float4*)&X[row*FIN + k0 + kq*4];
            As[kq*4+0][m] = v.x; As[kq*4+1][m] = v.y;
            As[kq*4+2][m] = v.z; As[kq*4+3][m] = v.w;
        }
        #pragma unroll
        for (int p=0;p<2;p++){
            int f = t + p*256;
            int kk = f >> 4;
            int nq = f & 15;
            float4 v = *(const float4*)&W[(size_t)(k0+kk)*F1 + n0 + nq*4];
            *(float4*)&Bs[kk][nq*4] = v;
        }
        __syncthreads();
        #pragma unroll
        for (int kk=0; kk<32; kk++){
            float4 a4 = *(const float4*)&As[kk][ty*4];
            float4 b4 = *(const float4*)&Bs[kk][tx*4];
            float av[4] = {a4.x,a4.y,a4.z,a4.w};
            float bv[4] = {b4.x,b4.y,b4.z,b4.w};
            #pragma unroll
            for (int r=0;r<4;r++)
                #pragma unroll
                for (int c=0;c<4;c++)
                    acc[r][c] = fmaf(av[r], bv[c], acc[r][c]);
        }
        __syncthreads();
    }
    // fused el/er: head h spans 32 cols; this thread's 4 cols lie in one head
    int h = (bx<<1) + (tx>>3);
    int basew = h*D1N + (tx&7)*4;
    float4 wl = *(const float4*)&al[basew];
    float4 wr = *(const float4*)&ar[basew];
    float pl[4], pr[4];
    #pragma unroll
    for (int r=0;r<4;r++){
        pl[r] = acc[r][0]*wl.x + acc[r][1]*wl.y + acc[r][2]*wl.z + acc[r][3]*wl.w;
        pr[r] = acc[r][0]*wr.x + acc[r][1]*wr.y + acc[r][2]*wr.z + acc[r][3]*wr.w;
    }
    #pragma unroll
    for (int msk=1; msk<8; msk<<=1){
        #pragma unroll
        for (int r=0;r<4;r++){
            pl[r] += __shfl_xor(pl[r], msk);
            pr[r] += __shfl_xor(pr[r], msk);
        }
    }
    #pragma unroll
    for (int r=0;r<4;r++){
        int row = m0 + ty*4 + r;
        if (row < M){
            union { uint2 u; __half2 h2[2]; } P;
            P.h2[0] = __floats2half2_rn(acc[r][0], acc[r][1]);
            P.h2[1] = __floats2half2_rn(acc[r][2], acc[r][3]);
            *(uint2*)&FT[(size_t)row*F1 + n0 + tx*4] = P.u;
            if ((tx & 7) == 0){
                el[row*H1N + h] = pl[r];
                er[row*H1N + h] = pr[r];
            }
        }
    }
}

// ---------------- layer-1 softmax + aggregation + relu: wave per node ----------------
__global__ __launch_bounds__(256) void k_agg1(const __half* __restrict__ FT,
                      const float* __restrict__ el, const float* __restrict__ er,
                      const int* __restrict__ rowptr, const int* __restrict__ adj,
                      float* __restrict__ hout, int n){
    int node = (blockIdx.x*256 + threadIdx.x) >> 6;
    int l = threadIdx.x & 63;
    if (node >= n) return;
    int rs = rowptr[node];
    int deg = rowptr[node+1] - rs;

    // pass 1: online softmax stats per head (lane = 8 edges x 8 heads)
    int h = l & 7, je = l >> 3;
    float erh = er[node*H1N + h];
    float m = -1e30f, ssum = 0.f;
    for (int j0 = 0; j0 < deg; j0 += 8){
        int j = j0 + je;
        if (j < deg){
            int s = adj[rs + j];
            float e = leaky(el[s*H1N + h] + erh);
            if (e > m){ ssum = ssum*__expf(m - e) + 1.f; m = e; }
            else ssum += __expf(e - m);
        }
    }
    #pragma unroll
    for (int msk=8; msk<64; msk<<=1){
        float m2 = __shfl_xor(m, msk);
        float s2 = __shfl_xor(ssum, msk);
        float nm = fmaxf(m, m2);
        ssum = ssum*__expf(m - nm) + s2*__expf(m2 - nm);
        m = nm;
    }

    // pass 2: lane owns elements [4l,4l+4) => head h2 = l>>3
    int h2 = l >> 3;
    float m2 = __shfl(m, h2);
    float s2 = __shfl(ssum, h2);
    float inv = 1.f / fmaxf(s2, 1e-16f);
    float erh2 = er[node*H1N + h2];
    float ax=0.f, ay=0.f, az=0.f, aw=0.f;
    int j = 0;
    for (; j + 8 <= deg; j += 8){
        int sv[8];
        #pragma unroll
        for (int i=0;i<8;i++) sv[i] = adj[rs+j+i];
        float av[8];
        #pragma unroll
        for (int i=0;i<8;i++)
            av[i] = __expf(leaky(el[sv[i]*H1N + h2] + erh2) - m2);
        #pragma unroll
        for (int i=0;i<8;i++){
            union { uint2 u; __half2 h2v[2]; } U;
            U.u = *(const uint2*)&FT[(size_t)sv[i]*F1 + l*4];
            float2 f01 = __half22float2(U.h2v[0]);
            float2 f23 = __half22float2(U.h2v[1]);
            ax = fmaf(av[i], f01.x, ax); ay = fmaf(av[i], f01.y, ay);
            az = fmaf(av[i], f23.x, az); aw = fmaf(av[i], f23.y, aw);
        }
    }
    for (; j < deg; j++){
        int s = adj[rs + j];
        float a = __expf(leaky(el[s*H1N + h2] + erh2) - m2);
        union { uint2 u; __half2 h2v[2]; } U;
        U.u = *(const uint2*)&FT[(size_t)s*F1 + l*4];
        float2 f01 = __half22float2(U.h2v[0]);
        float2 f23 = __half22float2(U.h2v[1]);
        ax = fmaf(a, f01.x, ax); ay = fmaf(a, f01.y, ay);
        az = fmaf(a, f23.x, az); aw = fmaf(a, f23.y, aw);
    }
    ax *= inv; ay *= inv; az *= inv; aw *= inv;
    *(float4*)&hout[(size_t)node*F1 + l*4] =
        make_float4(fmaxf(ax,0.f), fmaxf(ay,0.f), fmaxf(az,0.f), fmaxf(aw,0.f));
}

// ---------------- GEMM2: [M,256]@[256,40] -> fp16 padded [M,64] + fused el2/er2 ----------------
__global__ __launch_bounds__(256) void k_gemm2(const float* __restrict__ Hm,
                                               const float* __restrict__ W,
                                               const float* __restrict__ al2,
                                               const float* __restrict__ ar2,
                                               __half* __restrict__ FT2,
                                               float* __restrict__ el2,
                                               float* __restrict__ er2, int M){
    __shared__ float W2s[F1*NCLS];   // [k][c] flat
    __shared__ float hs[128][33];
    int t = threadIdx.x;
    for (int i = t; i < F1*NCLS; i += 256) W2s[i] = W[i];
    int r0 = blockIdx.x*128;
    int rr = t & 63;
    int cg = t >> 6;
    int c0 = cg*10;
    float acc[2][10] = {};
    for (int k0 = 0; k0 < F1; k0 += 32){
        __syncthreads();
        #pragma unroll
        for (int p=0;p<4;p++){
            int f = t + p*256;
            int row = f >> 3;
            int kq = f & 7;
            int gr = r0 + row;
            float4 v = make_float4(0.f,0.f,0.f,0.f);
            if (gr < M) v = *(const float4*)&Hm[(size_t)gr*F1 + k0 + kq*4];
            hs[row][kq*4+0] = v.x; hs[row][kq*4+1] = v.y;
            hs[row][kq*4+2] = v.z; hs[row][kq*4+3] = v.w;
        }
        __syncthreads();
        #pragma unroll
        for (int k=0;k<32;k++){
            float a0 = hs[rr][k], a1 = hs[rr+64][k];
            const float* wp = &W2s[(k0+k)*NCLS + c0];
            #pragma unroll
            for (int c=0;c<10;c+=2){
                float2 w = *(const float2*)&wp[c];
                acc[0][c]   = fmaf(a0, w.x, acc[0][c]);
                acc[0][c+1] = fmaf(a0, w.y, acc[0][c+1]);
                acc[1][c]   = fmaf(a1, w.x, acc[1][c]);
                acc[1][c+1] = fmaf(a1, w.y, acc[1][c+1]);
            }
        }
    }
    float pl[2] = {0.f,0.f}, pr[2] = {0.f,0.f};
    #pragma unroll
    for (int c=0;c<10;c++){
        float a2l = al2[c0+c], a2r = ar2[c0+c];
        pl[0] = fmaf(acc[0][c], a2l, pl[0]); pr[0] = fmaf(acc[0][c], a2r, pr[0]);
        pl[1] = fmaf(acc[1][c], a2l, pl[1]); pr[1] = fmaf(acc[1][c], a2r, pr[1]);
    }
    #pragma unroll
    for (int i=0;i<2;i++){
        int gr = r0 + rr + i*64;
        if (gr < M){
            #pragma unroll
            for (int c=0;c<10;c+=2){
                __half2 hp = __floats2half2_rn(acc[i][c], acc[i][c+1]);
                *(__half2*)&FT2[(size_t)gr*FT2P + c0 + c] = hp;
            }
            atomicAdd(&el2[gr], pl[i]);
            atomicAdd(&er2[gr], pr[i]);
        }
    }
}

// ---------------- layer-2 softmax + aggregation ----------------
__global__ __launch_bounds__(256) void k_agg2(const __half* __restrict__ FT2,
                      const float* __restrict__ el, const float* __restrict__ er,
                      const int* __restrict__ rowptr, const int* __restrict__ adj,
                      float* __restrict__ out, int n){
    int node = (blockIdx.x*256 + threadIdx.x) >> 6;
    int l = threadIdx.x & 63;
    if (node >= n) return;
    int rs = rowptr[node];
    int deg = rowptr[node+1] - rs;
    float ern = er[node];
    float m = -1e30f, ssum = 0.f;
    for (int j = l; j < deg; j += 64){
        int s = adj[rs + j];
        float e = leaky(el[s] + ern);
        if (e > m){ ssum = ssum*__expf(m - e) + 1.f; m = e; }
        else ssum += __expf(e - m);
    }
    #pragma unroll
    for (int msk=1; msk<64; msk<<=1){
        float mm = __shfl_xor(m, msk);
        float s2 = __shfl_xor(ssum, msk);
        float nm = fmaxf(m, mm);
        ssum = ssum*__expf(m - nm) + s2*__expf(mm - nm);
        m = nm;
    }
    float inv = 1.f / fmaxf(ssum, 1e-16f);
    float acc = 0.f;
    int j = 0;
    for (; j + 8 <= deg; j += 8){
        int sv[8];
        #pragma unroll
        for (int i=0;i<8;i++) sv[i] = adj[rs+j+i];
        float av[8];
        #pragma unroll
        for (int i=0;i<8;i++)
            av[i] = __expf(leaky(el[sv[i]] + ern) - m);
        if (l < NCLS){
            #pragma unroll
            for (int i=0;i<8;i++){
                float f = __half2float(FT2[(size_t)sv[i]*FT2P + l]);
                acc = fmaf(av[i], f, acc);
            }
        }
    }
    for (; j < deg; j++){
        int s = adj[rs + j];
        float a = __expf(leaky(el[s] + ern) - m);
        if (l < NCLS) acc = fmaf(a, __half2float(FT2[(size_t)s*FT2P + l]), acc);
    }
    if (l < NCLS) out[(size_t)node*NCLS + l] = acc * inv;
}

extern "C" void kernel_launch(void* const* d_in, const int* in_sizes, int n_in,
                              void* d_out, int out_size, void* d_ws, size_t ws_size,
                              hipStream_t stream){
    const float* x   = (const float*)d_in[0];
    const float* W1  = (const float*)d_in[1];
    const float* al1 = (const float*)d_in[2];
    const float* ar1 = (const float*)d_in[3];
    const float* W2  = (const float*)d_in[4];
    const float* al2 = (const float*)d_in[5];
    const float* ar2 = (const float*)d_in[6];
    const int*   src = (const int*)d_in[7];
    const int*   dst = (const int*)d_in[8];
    int E = in_sizes[7];
    int n = in_sizes[0] / FIN;   // 20000

    char* ws = (char*)d_ws;
    size_t off = 0;
    auto alloc = [&](size_t bytes)->void*{
        void* p = ws + off; off += (bytes + 255) & ~(size_t)255; return p;
    };
    __half* ft1h  = (__half*)alloc((size_t)n*F1*2);
    float*  hbuf  = (float*)alloc((size_t)n*F1*4);
    __half* ft2h  = (__half*)alloc((size_t)n*FT2P*2);
    float*  el1   = (float*)alloc((size_t)n*H1N*4);
    float*  er1   = (float*)alloc((size_t)n*H1N*4);
    int*    rowptr= (int*)alloc((size_t)(n+1)*4);
    int*    adj   = (int*)alloc((size_t)E*4);
    size_t  z0    = off;                       // zero-region start
    int*    deg   = (int*)alloc((size_t)n*4);
    float*  el2   = (float*)alloc((size_t)n*4);
    float*  er2   = (float*)alloc((size_t)n*4);
    size_t  z1    = off;                       // zero-region end

    int nb_e = (E + 255)/256;

    hipMemsetAsync(ws + z0, 0, z1 - z0, stream);   // deg + el2 + er2
    k_hist   <<<nb_e, 256, 0, stream>>>(dst, deg, E);
    k_scan   <<<1, 1024, 0, stream>>>(deg, rowptr, n, E);
    k_scatter<<<nb_e, 256, 0, stream>>>(src, dst, rowptr, deg, adj, E);

    k_gemm1  <<<((n+63)/64)*4, 256, 0, stream>>>(x, W1, al1, ar1, ft1h, el1, er1, n);
    k_agg1   <<<(n+3)/4, 256, 0, stream>>>(ft1h, el1, er1, rowptr, adj, hbuf, n);

    k_gemm2  <<<(n+127)/128, 256, 0, stream>>>(hbuf, W2, al2, ar2, ft2h, el2, er2, n);
    k_agg2   <<<(n+3)/4, 256, 0, stream>>>(ft2h, el2, er2, rowptr, adj, (float*)d_out, n);
}

// Round 7
// 212.060 us; speedup vs baseline: 1.2767x; 1.1591x over previous
//
#include <hip/hip_runtime.h>
#include <hip/hip_fp16.h>

#define FIN 128
#define F1 256      // H1*D1
#define H1N 8
#define D1N 32
#define NCLS 40
#define FT2P 64     // padded row stride for ft2 (halves)
#define W2PITCH 260 // LDS pitch for transposed W2 (bank-friendly, 8B-aligned rows)
#define NEG 0.2f

static __device__ __forceinline__ float leaky(float x){ return x >= 0.f ? x : NEG*x; }

// ---------------- CSR build ----------------
__global__ void k_hist(const int* __restrict__ dst, int* __restrict__ deg, int E){
    int e = blockIdx.x*256 + threadIdx.x;
    if (e < E) atomicAdd(&deg[dst[e]], 1);
}

__global__ void k_scan1(const int* __restrict__ deg, int* __restrict__ rowptr,
                        int* __restrict__ bsum, int n){
    __shared__ int s[256];
    int t = threadIdx.x;
    int i = blockIdx.x*256 + t;
    int v = (i < n) ? deg[i] : 0;
    s[t] = v;
    __syncthreads();
    for (int off=1; off<256; off<<=1){
        int y = (t >= off) ? s[t-off] : 0;
        __syncthreads();
        if (t >= off) s[t] += y;
        __syncthreads();
    }
    if (i < n) rowptr[i] = s[t] - v;          // exclusive, pre-offset
    if (t == 255) bsum[blockIdx.x] = s[255];
}

__global__ void k_scan2(int* __restrict__ rowptr, const int* __restrict__ bsum,
                        int n, int E){
    int b = blockIdx.x;
    int l = threadIdx.x & 63;
    int v = 0;
    for (int j = l; j < b; j += 64) v += bsum[j];
    for (int msk=1; msk<64; msk<<=1) v += __shfl_xor(v, msk);
    int i = b*256 + threadIdx.x;
    if (i < n) rowptr[i] += v;
    else if (i == n) rowptr[n] = E;
}

__global__ void k_scatter(const int* __restrict__ src, const int* __restrict__ dst,
                          const int* __restrict__ rowptr, int* __restrict__ deg,
                          int* __restrict__ adj, int E){
    int e = blockIdx.x*256 + threadIdx.x;
    if (e < E){
        int d = dst[e];
        int pos = atomicSub(&deg[d], 1) - 1;
        adj[rowptr[d] + pos] = src[e];
    }
}

// ---------------- GEMM1: [M,128]@[128,256] -> fp16 FT + fused el/er ----------------
__global__ __launch_bounds__(256) void k_gemm1(const float* __restrict__ X,
                                               const float* __restrict__ W,
                                               const float* __restrict__ al,
                                               const float* __restrict__ ar,
                                               __half* __restrict__ FT,
                                               float* __restrict__ el,
                                               float* __restrict__ er, int M){
    __shared__ float As[32][68];   // As[k][m]
    __shared__ float Bs[32][68];   // Bs[k][n]
    int t = threadIdx.x;
    int bx = blockIdx.x & 3;
    int by = blockIdx.x >> 2;
    int m0 = by*64, n0 = bx*64;
    int ty = t >> 4, tx = t & 15;
    float acc[4][4] = {};
    for (int k0 = 0; k0 < FIN; k0 += 32){
        #pragma unroll
        for (int p=0;p<2;p++){
            int f = t + p*256;
            int m = f >> 3;
            int kq = f & 7;
            int row = m0 + m;
            float4 v = make_float4(0.f,0.f,0.f,0.f);
            if (row < M) v = *(const float4*)&X[row*FIN + k0 + kq*4];
            As[kq*4+0][m] = v.x; As[kq*4+1][m] = v.y;
            As[kq*4+2][m] = v.z; As[kq*4+3][m] = v.w;
        }
        #pragma unroll
        for (int p=0;p<2;p++){
            int f = t + p*256;
            int kk = f >> 4;
            int nq = f & 15;
            float4 v = *(const float4*)&W[(size_t)(k0+kk)*F1 + n0 + nq*4];
            *(float4*)&Bs[kk][nq*4] = v;
        }
        __syncthreads();
        #pragma unroll
        for (int kk=0; kk<32; kk++){
            float4 a4 = *(const float4*)&As[kk][ty*4];
            float4 b4 = *(const float4*)&Bs[kk][tx*4];
            float av[4] = {a4.x,a4.y,a4.z,a4.w};
            float bv[4] = {b4.x,b4.y,b4.z,b4.w};
            #pragma unroll
            for (int r=0;r<4;r++)
                #pragma unroll
                for (int c=0;c<4;c++)
                    acc[r][c] = fmaf(av[r], bv[c], acc[r][c]);
        }
        __syncthreads();
    }
    // fused el/er: head h spans 32 cols; this thread's 4 cols lie in one head
    int h = (bx<<1) + (tx>>3);
    int basew = h*D1N + (tx&7)*4;
    float4 wl = *(const float4*)&al[basew];
    float4 wr = *(const float4*)&ar[basew];
    float pl[4], pr[4];
    #pragma unroll
    for (int r=0;r<4;r++){
        pl[r] = acc[r][0]*wl.x + acc[r][1]*wl.y + acc[r][2]*wl.z + acc[r][3]*wl.w;
        pr[r] = acc[r][0]*wr.x + acc[r][1]*wr.y + acc[r][2]*wr.z + acc[r][3]*wr.w;
    }
    #pragma unroll
    for (int msk=1; msk<8; msk<<=1){
        #pragma unroll
        for (int r=0;r<4;r++){
            pl[r] += __shfl_xor(pl[r], msk);
            pr[r] += __shfl_xor(pr[r], msk);
        }
    }
    #pragma unroll
    for (int r=0;r<4;r++){
        int row = m0 + ty*4 + r;
        if (row < M){
            union { uint2 u; __half2 h2[2]; } P;
            P.h2[0] = __floats2half2_rn(acc[r][0], acc[r][1]);
            P.h2[1] = __floats2half2_rn(acc[r][2], acc[r][3]);
            *(uint2*)&FT[(size_t)row*F1 + n0 + tx*4] = P.u;
            if ((tx & 7) == 0){
                el[row*H1N + h] = pl[r];
                er[row*H1N + h] = pr[r];
            }
        }
    }
}

// ---- layer-1 softmax + aggregation + relu + FUSED GEMM2/el2/er2: wave per node ----
__global__ __launch_bounds__(256) void k_agg1(const __half* __restrict__ FT,
                      const float* __restrict__ el, const float* __restrict__ er,
                      const float* __restrict__ W2,      // [256][40] fp32
                      const float* __restrict__ al2, const float* __restrict__ ar2,
                      const int* __restrict__ rowptr, const int* __restrict__ adj,
                      __half* __restrict__ FT2, float* __restrict__ el2,
                      float* __restrict__ er2, int n, int nwTot){
    __shared__ __half W2h[40*W2PITCH];   // transposed: W2h[c][k], ~20.3 KB
    __shared__ float  hst[4][260];       // per-wave h-row staging
    int t = threadIdx.x;
    // stage W2 transposed to fp16 (once per block, reused for all nodes)
    for (int e = t; e < 256*40; e += 256){
        int k = e / 40, c = e - k*40;
        W2h[c*W2PITCH + k] = __float2half_rn(W2[e]);
    }
    __syncthreads();

    int w = t >> 6, l = t & 63;
    int h = l & 7, je = l >> 3;        // pass-1 mapping
    int h2 = l >> 3;                   // pass-2 mapping
    int c = (l < 40) ? l : (l - 40);   // epilogue output column (lanes>=40 duplicate)
    float keep = (l < NCLS) ? 1.f : 0.f;
    float a2l = al2[c], a2r = ar2[c];
    const __half* wrow = &W2h[c*W2PITCH];
    float* hp = &hst[w][0];

    for (int node = blockIdx.x*4 + w; node < n; node += nwTot){
        int rs = rowptr[node];
        int deg = rowptr[node+1] - rs;

        // pass 1: online softmax stats per head (lane = 8 edges x 8 heads)
        float erh = er[node*H1N + h];
        float m = -1e30f, ssum = 0.f;
        for (int j0 = 0; j0 < deg; j0 += 8){
            int j = j0 + je;
            if (j < deg){
                int s = adj[rs + j];
                float e = leaky(el[s*H1N + h] + erh);
                if (e > m){ ssum = ssum*__expf(m - e) + 1.f; m = e; }
                else ssum += __expf(e - m);
            }
        }
        #pragma unroll
        for (int msk=8; msk<64; msk<<=1){
            float m2 = __shfl_xor(m, msk);
            float s2 = __shfl_xor(ssum, msk);
            float nm = fmaxf(m, m2);
            ssum = ssum*__expf(m - nm) + s2*__expf(m2 - nm);
            m = nm;
        }

        // pass 2: lane owns elements [4l,4l+4)
        float m2 = __shfl(m, h2);
        float s2 = __shfl(ssum, h2);
        float inv = 1.f / fmaxf(s2, 1e-16f);
        float erh2 = er[node*H1N + h2];
        float ax=0.f, ay=0.f, az=0.f, aw=0.f;
        int j = 0;
        for (; j + 8 <= deg; j += 8){
            int sv[8];
            #pragma unroll
            for (int i=0;i<8;i++) sv[i] = adj[rs+j+i];
            float av[8];
            #pragma unroll
            for (int i=0;i<8;i++)
                av[i] = __expf(leaky(el[sv[i]*H1N + h2] + erh2) - m2);
            #pragma unroll
            for (int i=0;i<8;i++){
                union { uint2 u; __half2 h2v[2]; } U;
                U.u = *(const uint2*)&FT[(size_t)sv[i]*F1 + l*4];
                float2 f01 = __half22float2(U.h2v[0]);
                float2 f23 = __half22float2(U.h2v[1]);
                ax = fmaf(av[i], f01.x, ax); ay = fmaf(av[i], f01.y, ay);
                az = fmaf(av[i], f23.x, az); aw = fmaf(av[i], f23.y, aw);
            }
        }
        for (; j < deg; j++){
            int s = adj[rs + j];
            float a = __expf(leaky(el[s*H1N + h2] + erh2) - m2);
            union { uint2 u; __half2 h2v[2]; } U;
            U.u = *(const uint2*)&FT[(size_t)s*F1 + l*4];
            float2 f01 = __half22float2(U.h2v[0]);
            float2 f23 = __half22float2(U.h2v[1]);
            ax = fmaf(a, f01.x, ax); ay = fmaf(a, f01.y, ay);
            az = fmaf(a, f23.x, az); aw = fmaf(a, f23.y, aw);
        }
        // normalize + relu => h row elements [4l,4l+4)
        ax = fmaxf(ax*inv, 0.f); ay = fmaxf(ay*inv, 0.f);
        az = fmaxf(az*inv, 0.f); aw = fmaxf(aw*inv, 0.f);

        // ---- fused GEMM2 epilogue: out[c] = sum_k h[k] * W2[k][c] ----
        *(float4*)&hp[l*4] = make_float4(ax, ay, az, aw);
        __builtin_amdgcn_wave_barrier();
        asm volatile("s_waitcnt lgkmcnt(0)" ::: "memory");
        float out = 0.f;
        #pragma unroll 8
        for (int k0 = 0; k0 < 64; k0++){
            float4 hv = *(const float4*)&hp[k0*4];              // broadcast read
            __half2 wa = *(const __half2*)&wrow[k0*4];
            __half2 wb = *(const __half2*)&wrow[k0*4+2];
            float2 fa = __half22float2(wa), fb = __half22float2(wb);
            out = fmaf(hv.x, fa.x, out); out = fmaf(hv.y, fa.y, out);
            out = fmaf(hv.z, fb.x, out); out = fmaf(hv.w, fb.y, out);
        }
        __builtin_amdgcn_wave_barrier();   // keep next iter's hst write behind these reads
        float pl = keep * out * a2l;
        float pr = keep * out * a2r;
        #pragma unroll
        for (int msk=1; msk<64; msk<<=1){
            pl += __shfl_xor(pl, msk);
            pr += __shfl_xor(pr, msk);
        }
        if (l == 0){ el2[node] = pl; er2[node] = pr; }
        if (l < NCLS) FT2[(size_t)node*FT2P + l] = __float2half_rn(out);
    }
}

// ---------------- layer-2 softmax + aggregation ----------------
__global__ __launch_bounds__(256) void k_agg2(const __half* __restrict__ FT2,
                      const float* __restrict__ el, const float* __restrict__ er,
                      const int* __restrict__ rowptr, const int* __restrict__ adj,
                      float* __restrict__ out, int n){
    int node = (blockIdx.x*256 + threadIdx.x) >> 6;
    int l = threadIdx.x & 63;
    if (node >= n) return;
    int rs = rowptr[node];
    int deg = rowptr[node+1] - rs;
    float ern = er[node];
    float m = -1e30f, ssum = 0.f;
    for (int j = l; j < deg; j += 64){
        int s = adj[rs + j];
        float e = leaky(el[s] + ern);
        if (e > m){ ssum = ssum*__expf(m - e) + 1.f; m = e; }
        else ssum += __expf(e - m);
    }
    #pragma unroll
    for (int msk=1; msk<64; msk<<=1){
        float mm = __shfl_xor(m, msk);
        float s2 = __shfl_xor(ssum, msk);
        float nm = fmaxf(m, mm);
        ssum = ssum*__expf(m - nm) + s2*__expf(mm - nm);
        m = nm;
    }
    float inv = 1.f / fmaxf(ssum, 1e-16f);
    float acc = 0.f;
    int j = 0;
    for (; j + 8 <= deg; j += 8){
        int sv[8];
        #pragma unroll
        for (int i=0;i<8;i++) sv[i] = adj[rs+j+i];
        float av[8];
        #pragma unroll
        for (int i=0;i<8;i++)
            av[i] = __expf(leaky(el[sv[i]] + ern) - m);
        if (l < NCLS){
            #pragma unroll
            for (int i=0;i<8;i++){
                float f = __half2float(FT2[(size_t)sv[i]*FT2P + l]);
                acc = fmaf(av[i], f, acc);
            }
        }
    }
    for (; j < deg; j++){
        int s = adj[rs + j];
        float a = __expf(leaky(el[s] + ern) - m);
        if (l < NCLS) acc = fmaf(a, __half2float(FT2[(size_t)s*FT2P + l]), acc);
    }
    if (l < NCLS) out[(size_t)node*NCLS + l] = acc * inv;
}

extern "C" void kernel_launch(void* const* d_in, const int* in_sizes, int n_in,
                              void* d_out, int out_size, void* d_ws, size_t ws_size,
                              hipStream_t stream){
    const float* x   = (const float*)d_in[0];
    const float* W1  = (const float*)d_in[1];
    const float* al1 = (const float*)d_in[2];
    const float* ar1 = (const float*)d_in[3];
    const float* W2  = (const float*)d_in[4];
    const float* al2 = (const float*)d_in[5];
    const float* ar2 = (const float*)d_in[6];
    const int*   src = (const int*)d_in[7];
    const int*   dst = (const int*)d_in[8];
    int E = in_sizes[7];
    int n = in_sizes[0] / FIN;   // 20000

    char* ws = (char*)d_ws;
    size_t off = 0;
    auto alloc = [&](size_t bytes)->void*{
        void* p = ws + off; off += (bytes + 255) & ~(size_t)255; return p;
    };
    __half* ft1h  = (__half*)alloc((size_t)n*F1*2);
    __half* ft2h  = (__half*)alloc((size_t)n*FT2P*2);
    float*  el1   = (float*)alloc((size_t)n*H1N*4);
    float*  er1   = (float*)alloc((size_t)n*H1N*4);
    float*  el2   = (float*)alloc((size_t)n*4);
    float*  er2   = (float*)alloc((size_t)n*4);
    int*    rowptr= (int*)alloc((size_t)(n+1)*4);
    int*    adj   = (int*)alloc((size_t)E*4);
    int*    bsum  = (int*)alloc((size_t)((n+255)/256)*4);
    int*    deg   = (int*)alloc((size_t)n*4);

    int nb_e = (E + 255)/256;
    int nb_n = (n + 255)/256;

    hipMemsetAsync(deg, 0, (size_t)n*4, stream);
    k_hist   <<<nb_e, 256, 0, stream>>>(dst, deg, E);
    k_scan1  <<<nb_n, 256, 0, stream>>>(deg, rowptr, bsum, n);
    k_scan2  <<<(n+1+255)/256, 256, 0, stream>>>(rowptr, bsum, n, E);
    k_scatter<<<nb_e, 256, 0, stream>>>(src, dst, rowptr, deg, adj, E);

    k_gemm1  <<<((n+63)/64)*4, 256, 0, stream>>>(x, W1, al1, ar1, ft1h, el1, er1, n);

    int aggBlocks = 2500;                 // 4 waves/block, grid-stride over nodes
    k_agg1   <<<aggBlocks, 256, 0, stream>>>(ft1h, el1, er1, W2, al2, ar2,
                                             rowptr, adj, ft2h, el2, er2,
                                             n, aggBlocks*4);
    k_agg2   <<<(n+3)/4, 256, 0, stream>>>(ft2h, el2, er2, rowptr, adj,
                                           (float*)d_out, n);
}